// Round 10
// baseline (308.698 us; speedup 1.0000x reference)
//
#include <hip/hip_runtime.h>

// MADE / PixelCNN autoregressive inverse (all fp32, per reference).
//
// r0-r4: 6-barrier/16-wave skeleton ~179us (inner-loop-invariant).
// r7:    2-barrier/8-wave spine+helpers 146.5us (bit-exact, no spill).
// r9:    LDS-broadcast MACs == readlane MACs (151.9) -> MAC style irrelevant;
//        the serial chain's LDS/barrier hop structure is the cost.
//
// r10: two waves per net (A: layer0+1, B: layer2+out), NT=256, 1 wave/SIMD,
// waves_per_eu(1,1) -> full 512-reg unified budget per wave (336 weight
// floats fit; overflow goes to AGPRs, not memory -- r5's spill was the
// 256-budget at 2 waves/EU). Self-sufficiency kills helpers: wtap0(p+1) =
// W1_W.h0(p) and ntap0 read only A's OWN h0row writes (no sync); same for B
// with h1row. Exactly two cross-wave handoffs per pixel: h1(p) A->B (B1),
// raw mu/ls B->A (B2). y(p-1) never round-trips LDS on the chain: A computes
// it in-register from uniform xchg and feeds h0's W-tap directly; yb is only
// written for NEXT-row N-taps (off-chain). Off-chain DOTUs run while the
// other wave owns the chain. Chain model ~1500-2000 cy/px vs 5500 measured.

#define NT 256

__device__ __forceinline__ float elu(float x) { return x > 0.f ? x : expm1f(x); }

#define BAR() asm volatile("s_waitcnt lgkmcnt(0)\n\ts_barrier" ::: "memory")

// 64-dot via uniform-address LDS broadcast: acc{0..3} += W_[4q+m] * B_[4q+m]
#define DOTU(W_, B_)                                                  \
  _Pragma("unroll")                                                   \
  for (int q = 0; q < 16; ++q) {                                      \
    const float4 hq = *reinterpret_cast<const float4*>((B_) + 4*q);   \
    a0 += (W_)[4*q+0] * hq.x;                                         \
    a1 += (W_)[4*q+1] * hq.y;                                         \
    a2 += (W_)[4*q+2] * hq.z;                                         \
    a3 += (W_)[4*q+3] * hq.w;                                         \
  }

__global__ __launch_bounds__(NT)
__attribute__((amdgpu_waves_per_eu(1, 1)))
void made_ar_decode_k(
    const float* __restrict__ x,
    const float* __restrict__ mw0, const float* __restrict__ mb0,
    const float* __restrict__ mw1, const float* __restrict__ mb1,
    const float* __restrict__ mw2, const float* __restrict__ mb2,
    const float* __restrict__ mwo, const float* __restrict__ mbo,
    const float* __restrict__ lw0, const float* __restrict__ lb0,
    const float* __restrict__ lw1, const float* __restrict__ lb1,
    const float* __restrict__ lw2, const float* __restrict__ lb2,
    const float* __restrict__ lwo, const float* __restrict__ lbo,
    float* __restrict__ out)
{
  const int b    = blockIdx.x;
  const int tid  = threadIdx.x;
  const int wave = tid >> 6;       // 0:A-mu 1:A-lv 2:B-mu 3:B-lv
  const int role = wave >> 1;      // 0:A (layer0+1)  1:B (layer2+out)
  const int net  = wave & 1;       // 0 = mu, 1 = lv
  const int ch   = tid & 63;       // lane == channel

  // parity double-buffered row caches; pcol = spatial col + 1; pad cols 0,9
  // (and yb pad row 0) are never written -> permanent zeros ('SAME' border).
  __shared__ __align__(16) float h0row[2][2][10][64]; // [net][par][pcol][ch] (A-private)
  __shared__ __align__(16) float h1row[2][2][10][64]; // A writes, B reads
  __shared__ __align__(16) float yb[2][9][10][4];     // [net][prow][pcol][c] (A-private)
  __shared__ __align__(16) float xchg[2][4];          // [net][c] raw out sums (B -> A)
  __shared__ float xls[256];

  for (int k = tid; k < 2*2*10*64; k += NT) {
    (&h0row[0][0][0][0])[k] = 0.f;
    (&h1row[0][0][0][0])[k] = 0.f;
  }
  for (int k = tid; k < 2*9*10*4; k += NT) (&yb[0][0][0][0])[k] = 0.f;
  xls[tid] = x[b*256 + tid];   // [c][i][j] flat = c*64 + p

  __syncthreads();

  if (role == 0) {
    // ================= A: epi + h0 + full layer-1 =================
    const float* w0g = net ? lw0 : mw0;
    const float* w1g = net ? lw1 : mw1;
    float w0t[16];            // w0 mask-A taps [t*4+ic], t: NW,N,NE,W
    float wc1[64], wW1[64];   // W1 center / W column (lane = out ch)
    float n1a[64], n1b[64], n1c[64];  // W1 NW,N,NE columns (allocator -> AGPR)
    {
      const int KH[4] = {0,0,0,1};
      const int KW[4] = {0,1,2,0};
#pragma unroll
      for (int t = 0; t < 4; ++t)
#pragma unroll
        for (int ic = 0; ic < 4; ++ic)
          w0t[t*4+ic] = w0g[((ch*4 + ic)*3 + KH[t])*3 + KW[t]];
    }
#pragma unroll
    for (int q = 0; q < 64; ++q) {
      wc1[q] = w1g[((ch*64 + q)*3 + 1)*3 + 1];
      wW1[q] = w1g[((ch*64 + q)*3 + 1)*3 + 0];
      n1a[q] = w1g[((ch*64 + q)*3 + 0)*3 + 0];
      n1b[q] = w1g[((ch*64 + q)*3 + 0)*3 + 1];
      n1c[q] = w1g[((ch*64 + q)*3 + 0)*3 + 2];
    }
    const float bA = (net ? lb0 : mb0)[ch];
    const float bB = (net ? lb1 : mb1)[ch];
    float boM[4], boL[4];
#pragma unroll
    for (int c = 0; c < 4; ++c) { boM[c] = mbo[c]; boL[c] = lbo[c]; }
    // pin only the hot per-pixel columns as VGPRs (<=144); N-tap columns are
    // left to the allocator (expected AGPR placement at 1 wave/SIMD).
#pragma unroll
    for (int k = 0; k < 16; ++k) asm volatile("" : "+v"(w0t[k]));
#pragma unroll
    for (int q = 0; q < 64; ++q) asm volatile("" : "+v"(wc1[q]));
#pragma unroll
    for (int q = 0; q < 64; ++q) asm volatile("" : "+v"(wW1[q]));

    float ntap0r = 0.f, wtap0r = 0.f;            // for pixel p (init: pads)
    float y0 = 0.f, y1 = 0.f, y2 = 0.f, y3 = 0.f; // y(p-1), all lanes
    float lsacc = 0.f;

#pragma unroll 1
    for (int p = 0; p < 64; ++p) {
      const int i = p >> 3, j = p & 7, cur = i & 1;

      // ---- chain: epi(p-1) -> h0(p) -> c1 -> h1(p) ----
      if (p > 0) {
        const int pp = p - 1;
        const float4 m4 = *reinterpret_cast<const float4*>(&xchg[0][0]);
        const float4 l4 = *reinterpret_cast<const float4*>(&xchg[1][0]);
        const float ls0 = 0.5f*(l4.x + boL[0]), ls1 = 0.5f*(l4.y + boL[1]);
        const float ls2 = 0.5f*(l4.z + boL[2]), ls3 = 0.5f*(l4.w + boL[3]);
        y0 = (xls[0*64+pp] - (m4.x + boM[0])) / (expf(ls0) + 1e-12f);
        y1 = (xls[1*64+pp] - (m4.y + boM[1])) / (expf(ls1) + 1e-12f);
        y2 = (xls[2*64+pp] - (m4.z + boM[2])) / (expf(ls2) + 1e-12f);
        y3 = (xls[3*64+pp] - (m4.w + boM[3])) / (expf(ls3) + 1e-12f);
        if (ch == 0)
          *reinterpret_cast<float4*>(&yb[net][(pp>>3)+1][(pp&7)+1][0]) =
              make_float4(y0, y1, y2, y3);
        if (net == 1) lsacc += (ls0 + ls1) + (ls2 + ls3);
      }
      float acc = bA;
      {
        const float4 yNW = *reinterpret_cast<const float4*>(&yb[net][i][j    ][0]);
        const float4 yN  = *reinterpret_cast<const float4*>(&yb[net][i][j + 1][0]);
        const float4 yNE = *reinterpret_cast<const float4*>(&yb[net][i][j + 2][0]);
        acc += w0t[0]*yNW.x + w0t[1]*yNW.y + w0t[2]*yNW.z + w0t[3]*yNW.w;
        acc += w0t[4]*yN.x  + w0t[5]*yN.y  + w0t[6]*yN.z  + w0t[7]*yN.w;
        acc += w0t[8]*yNE.x + w0t[9]*yNE.y + w0t[10]*yNE.z + w0t[11]*yNE.w;
        if (j > 0)   // W-tap = y(p-1), in-register
          acc += w0t[12]*y0 + w0t[13]*y1 + w0t[14]*y2 + w0t[15]*y3;
      }
      const float h0v = elu(acc);
      h0row[net][cur][j + 1][ch] = h0v;

      float c1;
      {
        float a0 = 0.f, a1 = 0.f, a2 = 0.f, a3 = 0.f;
        DOTU(wc1, &h0row[net][cur][j + 1][0]);
        c1 = (a0 + a1) + (a2 + a3);
      }
      const float h1v = elu(((c1 + bB) + ntap0r) + wtap0r);
      h1row[net][cur][j + 1][ch] = h1v;

      BAR();   // B1: h1(p) -> B

      // ---- off-chain (B owns the chain now): taps for p+1, own data only ----
      if (p < 63) {
        const int p2 = p + 1, i2 = p2 >> 3, j2 = p2 & 7;
        if (i2 >= 1) {
          const int sp = (i2 - 1) & 1;
          float a0 = 0.f, a1 = 0.f, a2 = 0.f, a3 = 0.f;
          DOTU(n1a, &h0row[net][sp][j2    ][0]);
          DOTU(n1b, &h0row[net][sp][j2 + 1][0]);
          DOTU(n1c, &h0row[net][sp][j2 + 2][0]);
          ntap0r = (a0 + a1) + (a2 + a3);
        } else ntap0r = 0.f;
        if (j2 > 0) {
          float a0 = 0.f, a1 = 0.f, a2 = 0.f, a3 = 0.f;
          DOTU(wW1, &h0row[net][cur][j + 1][0]);   // h0(p)
          wtap0r = (a0 + a1) + (a2 + a3);
        } else wtap0r = 0.f;
      }

      BAR();   // B2: xchg(p) -> A (next iteration's epi)
    }

    // final epi: y(63)
    {
      const float4 m4 = *reinterpret_cast<const float4*>(&xchg[0][0]);
      const float4 l4 = *reinterpret_cast<const float4*>(&xchg[1][0]);
      const float ls0 = 0.5f*(l4.x + boL[0]), ls1 = 0.5f*(l4.y + boL[1]);
      const float ls2 = 0.5f*(l4.z + boL[2]), ls3 = 0.5f*(l4.w + boL[3]);
      const float fy0 = (xls[0*64+63] - (m4.x + boM[0])) / (expf(ls0) + 1e-12f);
      const float fy1 = (xls[1*64+63] - (m4.y + boM[1])) / (expf(ls1) + 1e-12f);
      const float fy2 = (xls[2*64+63] - (m4.z + boM[2])) / (expf(ls2) + 1e-12f);
      const float fy3 = (xls[3*64+63] - (m4.w + boM[3])) / (expf(ls3) + 1e-12f);
      if (ch == 0)
        *reinterpret_cast<float4*>(&yb[net][8][8][0]) = make_float4(fy0, fy1, fy2, fy3);
      if (net == 1) lsacc += (ls0 + ls1) + (ls2 + ls3);
    }
    if (net == 1 && ch == 0) out[32*4*64 + b] = lsacc;

  } else {
    // ================= B: layer-2 + 1x1 out-conv =================
    const float* w2g = net ? lw2 : mw2;
    const float* wog = net ? lwo : mwo;
    float wc2[64], wW2[64], wo4[4];
    float n2a[64], n2b[64], n2c[64];  // W2 NW,N,NE (allocator -> AGPR)
#pragma unroll
    for (int q = 0; q < 64; ++q) {
      wc2[q] = w2g[((ch*64 + q)*3 + 1)*3 + 1];
      wW2[q] = w2g[((ch*64 + q)*3 + 1)*3 + 0];
      n2a[q] = w2g[((ch*64 + q)*3 + 0)*3 + 0];
      n2b[q] = w2g[((ch*64 + q)*3 + 0)*3 + 1];
      n2c[q] = w2g[((ch*64 + q)*3 + 0)*3 + 2];
    }
#pragma unroll
    for (int c = 0; c < 4; ++c) wo4[c] = wog[c*64 + ch];
    const float bC = (net ? lb2 : mb2)[ch];
#pragma unroll
    for (int q = 0; q < 64; ++q) asm volatile("" : "+v"(wc2[q]));
#pragma unroll
    for (int q = 0; q < 64; ++q) asm volatile("" : "+v"(wW2[q]));
#pragma unroll
    for (int c = 0; c < 4; ++c) asm volatile("" : "+v"(wo4[c]));

    float ntap1r = 0.f, wtap1r = 0.f;

#pragma unroll 1
    for (int p = 0; p < 64; ++p) {
      const int i = p >> 3, j = p & 7, cur = i & 1;

      BAR();   // B1: h1(p) visible

      // ---- chain: c2 -> h2 -> out butterfly -> xchg ----
      float c2;
      {
        float a0 = 0.f, a1 = 0.f, a2 = 0.f, a3 = 0.f;
        DOTU(wc2, &h1row[net][cur][j + 1][0]);
        c2 = (a0 + a1) + (a2 + a3);
      }
      const float h2v = elu(((c2 + bC) + ntap1r) + wtap1r);
      float s0 = wo4[0]*h2v, s1 = wo4[1]*h2v, s2 = wo4[2]*h2v, s3 = wo4[3]*h2v;
#pragma unroll
      for (int off = 32; off; off >>= 1) {
        s0 += __shfl_xor(s0, off, 64);
        s1 += __shfl_xor(s1, off, 64);
        s2 += __shfl_xor(s2, off, 64);
        s3 += __shfl_xor(s3, off, 64);
      }
      if (ch == 0)
        *reinterpret_cast<float4*>(&xchg[net][0]) = make_float4(s0, s1, s2, s3);

      BAR();   // B2: xchg(p) -> A

      // ---- off-chain (A owns the chain now): layer-2 taps for p+1 ----
      if (p < 63) {
        const int p2 = p + 1, i2 = p2 >> 3, j2 = p2 & 7;
        if (i2 >= 1) {
          const int sp = (i2 - 1) & 1;
          float a0 = 0.f, a1 = 0.f, a2 = 0.f, a3 = 0.f;
          DOTU(n2a, &h1row[net][sp][j2    ][0]);
          DOTU(n2b, &h1row[net][sp][j2 + 1][0]);
          DOTU(n2c, &h1row[net][sp][j2 + 2][0]);
          ntap1r = (a0 + a1) + (a2 + a3);
        } else ntap1r = 0.f;
        if (j2 > 0) {
          float a0 = 0.f, a1 = 0.f, a2 = 0.f, a3 = 0.f;
          DOTU(wW2, &h1row[net][cur][j + 1][0]);   // h1(p)
          wtap1r = (a0 + a1) + (a2 + a3);
        } else wtap1r = 0.f;
      }
    }
  }

  BAR();   // join: yb complete (incl. y(63))

  // copy-out: y from net-0's yb
  {
    const int c = tid >> 6, p = tid & 63;
    out[(b*4 + c)*64 + p] = yb[0][(p >> 3) + 1][(p & 7) + 1][c];
  }
}

extern "C" void kernel_launch(void* const* d_in, const int* in_sizes, int n_in,
                              void* d_out, int out_size, void* d_ws, size_t ws_size,
                              hipStream_t stream) {
  (void)in_sizes; (void)n_in; (void)out_size; (void)d_ws; (void)ws_size;
  made_ar_decode_k<<<dim3(32), dim3(NT), 0, stream>>>(
      (const float*)d_in[0],
      (const float*)d_in[1],  (const float*)d_in[2],
      (const float*)d_in[3],  (const float*)d_in[4],
      (const float*)d_in[5],  (const float*)d_in[6],
      (const float*)d_in[7],  (const float*)d_in[8],
      (const float*)d_in[9],  (const float*)d_in[10],
      (const float*)d_in[11], (const float*)d_in[12],
      (const float*)d_in[13], (const float*)d_in[14],
      (const float*)d_in[15], (const float*)d_in[16],
      (float*)d_out);
}

// Round 11
// 219.813 us; speedup vs baseline: 1.4044x; 1.4044x over previous
//
#include <hip/hip_runtime.h>

// MADE / PixelCNN autoregressive inverse (all fp32, per reference).
//
// Ledger: r0-r4 6-barrier/16-wave ~179us (inner-loop invariant). r7
// 2-barrier/8-wave spine+helpers 146.5us (best; bit-exact; VGPR 128, no
// spill). r9 DOTU==readlane (151.9) -> MAC style irrelevant. r10 2-wave
// deep chain 229us -> chain must stay on ONE wave per net; helpers matter.
//
// r11 = r7 with the helper schedule rebalanced by data availability:
//  * All W1 off-center taps for pixel p+1 need only h0(<=p); h0(p) is
//    visible at B1 of slot p -> W1 dots move to the helpers' POST-B1 phase
//    (previously idle), overlapping the spine's h1->c2->h2->butterfly.
//  * Pre-B1 keeps only W2 dots (need h1(p-1), visible pre-B1 of slot p).
//  * Max helper phase: 768 instr (r7's Ha) -> 512 (Hb post), balanced
//    against the spine's ~450/~700 cy phases.
//  * W1 partials (r1a/r1b/r1c) double-buffered by pixel parity: written in
//    slot p for p+1, read post-B1 of slot p+1 (2 barriers apart). W2
//    partials (r2a/r2b/r2c) single-buffered: write pre-B1, read post-B1.
// Roles per net: S (spine: epi,h0,c1 | h1,c2,h2,butterfly,xchg),
//  Ha: pre {W2NW,W2N} / post {W1NW};  Hb: pre {W2NE} / post {W1N,W1NE};
//  Hc: pre {W2W}     / post {W1W}.   (<=192 pinned floats each, r7-proven)
// LDS pad cols 0/9 are never written -> zero taps at borders for free.

#define NT 512

__device__ __forceinline__ float elu(float x) { return x > 0.f ? x : expm1f(x); }

__device__ __forceinline__ float rdlane(float v, int l) {
  return __int_as_float(__builtin_amdgcn_readlane(__float_as_int(v), l));
}

#define BAR() asm volatile("s_waitcnt lgkmcnt(0)\n\ts_barrier" ::: "memory")

// one 64-dot quarter-step: acc{0..3} += W_[4q+m] * (lane-q broadcast of F_ members)
#define DOT16(W_, F_)                                                \
  _Pragma("unroll")                                                  \
  for (int q = 0; q < 16; ++q) {                                     \
    a0 += (W_)[4*q+0] * rdlane((F_).x, q);                           \
    a1 += (W_)[4*q+1] * rdlane((F_).y, q);                           \
    a2 += (W_)[4*q+2] * rdlane((F_).z, q);                           \
    a3 += (W_)[4*q+3] * rdlane((F_).w, q);                           \
  }

#define FRAG(P_) (reinterpret_cast<const float4*>(P_)[ch & 15])

__global__ __launch_bounds__(NT)
__attribute__((amdgpu_waves_per_eu(2, 2)))
void made_ar_decode_k(
    const float* __restrict__ x,
    const float* __restrict__ mw0, const float* __restrict__ mb0,
    const float* __restrict__ mw1, const float* __restrict__ mb1,
    const float* __restrict__ mw2, const float* __restrict__ mb2,
    const float* __restrict__ mwo, const float* __restrict__ mbo,
    const float* __restrict__ lw0, const float* __restrict__ lb0,
    const float* __restrict__ lw1, const float* __restrict__ lb1,
    const float* __restrict__ lw2, const float* __restrict__ lb2,
    const float* __restrict__ lwo, const float* __restrict__ lbo,
    float* __restrict__ out)
{
  const int b    = blockIdx.x;
  const int tid  = threadIdx.x;
  const int wv   = tid >> 6;       // 0..7; SIMD pairing = (wv, wv+4)
  const int net  = wv & 1;         // 0 = mu, 1 = lv
  const int role = wv >> 1;        // 0:S  1:Hb  2:Ha  3:Hc
  const int ch   = tid & 63;       // lane == out channel

  // parity double-buffered row caches; pcol = spatial col + 1; pad cols 0,9
  // never written -> permanent zeros ('SAME' border).
  __shared__ __align__(16) float h0row[2][2][10][64]; // [net][par][pcol][ch]
  __shared__ __align__(16) float h1row[2][2][10][64];
  __shared__ __align__(16) float yb[2][9][10][4];     // [net][prow][pcol][c]
  __shared__ __align__(16) float xchg[2][2][4];       // [p&1][net][c]
  __shared__ float r1a[2][2][64], r1b[2][2][64], r1c[2][2][64]; // [pix&1][net][ch] W1 partials
  __shared__ float r2a[2][64], r2b[2][64], r2c[2][64];          // [net][ch] W2 partials
  __shared__ float xls[256];

  for (int k = tid; k < 2*2*10*64; k += NT) {
    (&h0row[0][0][0][0])[k] = 0.f;
    (&h1row[0][0][0][0])[k] = 0.f;
  }
  for (int k = tid; k < 2*9*10*4; k += NT) (&yb[0][0][0][0])[k] = 0.f;
  for (int k = tid; k < 2*2*64; k += NT) {
    (&r1a[0][0][0])[k] = 0.f;
    (&r1b[0][0][0])[k] = 0.f;
    (&r1c[0][0][0])[k] = 0.f;
  }
  if (tid < 256) xls[tid] = x[b*256 + tid];   // [c][i][j] flat = c*64 + p

  __syncthreads();   // uniform join after init

  if (role == 0) {
    // ================= S: serial spine =================
    const float* w0g = net ? lw0 : mw0;
    const float* w1g = net ? lw1 : mw1;
    const float* w2g = net ? lw2 : mw2;
    const float* wog = net ? lwo : mwo;
    const int KH[4] = {0,0,0,1};
    const int KW[4] = {0,1,2,0};
    float waux[16], wc1[64], wc2[64], wo4[4];
#pragma unroll
    for (int t = 0; t < 4; ++t)
#pragma unroll
      for (int ic = 0; ic < 4; ++ic)
        waux[t*4 + ic] = w0g[((ch*4 + ic)*3 + KH[t])*3 + KW[t]];
#pragma unroll
    for (int q = 0; q < 64; ++q) wc1[q] = w1g[((ch*64 + q)*3 + 1)*3 + 1];
#pragma unroll
    for (int q = 0; q < 64; ++q) wc2[q] = w2g[((ch*64 + q)*3 + 1)*3 + 1];
#pragma unroll
    for (int c = 0; c < 4; ++c) wo4[c] = wog[c*64 + ch];
    const float bA = (net ? lb0 : mb0)[ch];
    const float bB = (net ? lb1 : mb1)[ch];
    const float bC = (net ? lb2 : mb2)[ch];
    float boM[4], boL[4];
#pragma unroll
    for (int c = 0; c < 4; ++c) { boM[c] = mbo[c]; boL[c] = lbo[c]; }
#pragma unroll
    for (int k = 0; k < 16; ++k) asm volatile("" : "+v"(waux[k]));
#pragma unroll
    for (int q = 0; q < 64; ++q) asm volatile("" : "+v"(wc1[q]));
#pragma unroll
    for (int q = 0; q < 64; ++q) asm volatile("" : "+v"(wc2[q]));

    float lsacc = 0.f;

#pragma unroll 1
    for (int p = 0; p < 64; ++p) {
      const int i = p >> 3, j = p & 7, cur = i & 1, pb = p & 1;

      // ---- pre-B1: epi(p-1), h0(p), c1 ----
      if (p > 0) {
        const int pp = p - 1;
        const float4 m4 = *reinterpret_cast<const float4*>(&xchg[pp & 1][0][0]);
        const float4 l4 = *reinterpret_cast<const float4*>(&xchg[pp & 1][1][0]);
        float y0 = (xls[0*64+pp] - (m4.x + boM[0])) / (expf(0.5f*(l4.x + boL[0])) + 1e-12f);
        float y1 = (xls[1*64+pp] - (m4.y + boM[1])) / (expf(0.5f*(l4.y + boL[1])) + 1e-12f);
        float y2 = (xls[2*64+pp] - (m4.z + boM[2])) / (expf(0.5f*(l4.z + boL[2])) + 1e-12f);
        float y3 = (xls[3*64+pp] - (m4.w + boM[3])) / (expf(0.5f*(l4.w + boL[3])) + 1e-12f);
        if (ch == 0)
          *reinterpret_cast<float4*>(&yb[net][(pp>>3)+1][(pp&7)+1][0]) =
              make_float4(y0, y1, y2, y3);
      }
      float acc = bA;
#pragma unroll
      for (int t = 0; t < 4; ++t) {
        const float4 yv = *reinterpret_cast<const float4*>(&yb[net][i + KH[t]][j + KW[t]][0]);
        acc += waux[t*4+0]*yv.x + waux[t*4+1]*yv.y
             + waux[t*4+2]*yv.z + waux[t*4+3]*yv.w;
      }
      const float h0v = elu(acc);
      h0row[net][cur][j + 1][ch] = h0v;

      float c1;
      {
        float a0 = 0.f, a1 = 0.f, a2 = 0.f, a3 = 0.f;
#pragma unroll
        for (int q = 0; q < 16; ++q) {
          a0 += wc1[4*q+0] * rdlane(h0v, 4*q+0);
          a1 += wc1[4*q+1] * rdlane(h0v, 4*q+1);
          a2 += wc1[4*q+2] * rdlane(h0v, 4*q+2);
          a3 += wc1[4*q+3] * rdlane(h0v, 4*q+3);
        }
        c1 = (a0 + a1) + (a2 + a3);
      }

      BAR();   // B1: h0(p), c-partials visible

      // ---- post-B1: h1, c2, h2, out-conv ----
      const float h1v = elu(((c1 + bB) + (r1a[pb][net][ch] + r1b[pb][net][ch]))
                            + r1c[pb][net][ch]);
      h1row[net][cur][j + 1][ch] = h1v;

      float c2;
      {
        float a0 = 0.f, a1 = 0.f, a2 = 0.f, a3 = 0.f;
#pragma unroll
        for (int q = 0; q < 16; ++q) {
          a0 += wc2[4*q+0] * rdlane(h1v, 4*q+0);
          a1 += wc2[4*q+1] * rdlane(h1v, 4*q+1);
          a2 += wc2[4*q+2] * rdlane(h1v, 4*q+2);
          a3 += wc2[4*q+3] * rdlane(h1v, 4*q+3);
        }
        c2 = (a0 + a1) + (a2 + a3);
      }
      const float h2v = elu(((c2 + bC) + (r2a[net][ch] + r2b[net][ch]))
                            + r2c[net][ch]);

      float s0 = wo4[0]*h2v, s1 = wo4[1]*h2v, s2 = wo4[2]*h2v, s3 = wo4[3]*h2v;
#pragma unroll
      for (int off = 32; off; off >>= 1) {
        s0 += __shfl_xor(s0, off, 64);
        s1 += __shfl_xor(s1, off, 64);
        s2 += __shfl_xor(s2, off, 64);
        s3 += __shfl_xor(s3, off, 64);
      }
      if (ch == 0)
        *reinterpret_cast<float4*>(&xchg[p & 1][net][0]) = make_float4(s0, s1, s2, s3);
      if (net == 1 && ch == 0)
        lsacc += 0.5f*((s0 + boL[0]) + (s1 + boL[1]) + (s2 + boL[2]) + (s3 + boL[3]));

      BAR();   // B2
    }

    // final y(63) into yb (for the copy-out)
    {
      const float4 m4 = *reinterpret_cast<const float4*>(&xchg[1][0][0]);
      const float4 l4 = *reinterpret_cast<const float4*>(&xchg[1][1][0]);
      float y0 = (xls[0*64+63] - (m4.x + boM[0])) / (expf(0.5f*(l4.x + boL[0])) + 1e-12f);
      float y1 = (xls[1*64+63] - (m4.y + boM[1])) / (expf(0.5f*(l4.y + boL[1])) + 1e-12f);
      float y2 = (xls[2*64+63] - (m4.z + boM[2])) / (expf(0.5f*(l4.z + boL[2])) + 1e-12f);
      float y3 = (xls[3*64+63] - (m4.w + boM[3])) / (expf(0.5f*(l4.w + boL[3])) + 1e-12f);
      if (ch == 0)
        *reinterpret_cast<float4*>(&yb[net][8][8][0]) = make_float4(y0, y1, y2, y3);
    }
    if (net == 1 && ch == 0) out[32*4*64 + b] = lsacc;

  } else if (role == 1) {
    // ===== Hb: pre {W2 NE} ; post {W1 N, W1 NE (for p+1)} =====
    const float* w1g = net ? lw1 : mw1;
    const float* w2g = net ? lw2 : mw2;
    float w2ne[64], w1n[64], w1ne[64];
#pragma unroll
    for (int q = 0; q < 64; ++q) {
      w2ne[q] = w2g[((ch*64 + q)*3 + 0)*3 + 2];
      w1n [q] = w1g[((ch*64 + q)*3 + 0)*3 + 1];
      w1ne[q] = w1g[((ch*64 + q)*3 + 0)*3 + 2];
    }
#pragma unroll
    for (int q = 0; q < 64; ++q) {
      asm volatile("" : "+v"(w2ne[q]));
      asm volatile("" : "+v"(w1n[q]));
      asm volatile("" : "+v"(w1ne[q]));
    }
#pragma unroll 1
    for (int p = 0; p < 64; ++p) {
      const int i = p >> 3, j = p & 7, cur = i & 1, prv = cur ^ 1;
      {
        const float4 f = FRAG(&h1row[net][prv][j + 2][0]);
        float a0 = 0.f, a1 = 0.f, a2 = 0.f, a3 = 0.f;
        DOT16(w2ne, f);
        r2b[net][ch] = (a0 + a1) + (a2 + a3);
      }
      BAR();
      if (p < 63) {
        const int p2 = p + 1, i2 = p2 >> 3, j2 = p2 & 7;
        float v = 0.f;
        if (i2 >= 1) {
          const int sp = (i2 - 1) & 1;
          const float4 fN  = FRAG(&h0row[net][sp][j2 + 1][0]);
          const float4 fNE = FRAG(&h0row[net][sp][j2 + 2][0]);
          float a0 = 0.f, a1 = 0.f, a2 = 0.f, a3 = 0.f;
          DOT16(w1n,  fN);
          DOT16(w1ne, fNE);
          v = (a0 + a1) + (a2 + a3);
        }
        r1b[p2 & 1][net][ch] = v;
      }
      BAR();
    }

  } else if (role == 2) {
    // ===== Ha: pre {W2 NW, W2 N} ; post {W1 NW (for p+1)} =====
    const float* w1g = net ? lw1 : mw1;
    const float* w2g = net ? lw2 : mw2;
    float w2nw[64], w2n[64], w1nw[64];
#pragma unroll
    for (int q = 0; q < 64; ++q) {
      w2nw[q] = w2g[((ch*64 + q)*3 + 0)*3 + 0];
      w2n [q] = w2g[((ch*64 + q)*3 + 0)*3 + 1];
      w1nw[q] = w1g[((ch*64 + q)*3 + 0)*3 + 0];
    }
#pragma unroll
    for (int q = 0; q < 64; ++q) {
      asm volatile("" : "+v"(w2nw[q]));
      asm volatile("" : "+v"(w2n[q]));
      asm volatile("" : "+v"(w1nw[q]));
    }
#pragma unroll 1
    for (int p = 0; p < 64; ++p) {
      const int i = p >> 3, j = p & 7, cur = i & 1, prv = cur ^ 1;
      {
        const float4 fNW = FRAG(&h1row[net][prv][j    ][0]);
        const float4 fN  = FRAG(&h1row[net][prv][j + 1][0]);
        float a0 = 0.f, a1 = 0.f, a2 = 0.f, a3 = 0.f;
        DOT16(w2nw, fNW);
        DOT16(w2n,  fN);
        r2a[net][ch] = (a0 + a1) + (a2 + a3);
      }
      BAR();
      if (p < 63) {
        const int p2 = p + 1, i2 = p2 >> 3, j2 = p2 & 7;
        float v = 0.f;
        if (i2 >= 1) {
          const int sp = (i2 - 1) & 1;
          const float4 f = FRAG(&h0row[net][sp][j2][0]);
          float a0 = 0.f, a1 = 0.f, a2 = 0.f, a3 = 0.f;
          DOT16(w1nw, f);
          v = (a0 + a1) + (a2 + a3);
        }
        r1a[p2 & 1][net][ch] = v;
      }
      BAR();
    }

  } else {
    // ===== Hc: pre {W2 W vs h1(p-1)} ; post {W1 W vs h0(p) (for p+1)} =====
    const float* w1g = net ? lw1 : mw1;
    const float* w2g = net ? lw2 : mw2;
    float w2w[64], w1w[64];
#pragma unroll
    for (int q = 0; q < 64; ++q) {
      w2w[q] = w2g[((ch*64 + q)*3 + 1)*3 + 0];
      w1w[q] = w1g[((ch*64 + q)*3 + 1)*3 + 0];
    }
#pragma unroll
    for (int q = 0; q < 64; ++q) {
      asm volatile("" : "+v"(w2w[q]));
      asm volatile("" : "+v"(w1w[q]));
    }
#pragma unroll 1
    for (int p = 0; p < 64; ++p) {
      const int i = p >> 3, j = p & 7, cur = i & 1;
      {
        // pcol j: pad col 0 gives zero at j==0 automatically
        const float4 f = FRAG(&h1row[net][cur][j][0]);
        float a0 = 0.f, a1 = 0.f, a2 = 0.f, a3 = 0.f;
        DOT16(w2w, f);
        r2c[net][ch] = (a0 + a1) + (a2 + a3);
      }
      BAR();
      if (p < 63) {
        const int p2 = p + 1, j2 = p2 & 7;
        float v = 0.f;
        if (j2 > 0) {   // same row: W tap = h0(p), just written pre-B1
          const float4 f = FRAG(&h0row[net][cur][j + 1][0]);
          float a0 = 0.f, a1 = 0.f, a2 = 0.f, a3 = 0.f;
          DOT16(w1w, f);
          v = (a0 + a1) + (a2 + a3);
        }
        r1c[p2 & 1][net][ch] = v;
      }
      BAR();
    }
  }

  BAR();   // join: yb complete (incl. y(63))

  // copy-out: y from net-0's yb
  if (tid < 256) {
    const int c = tid >> 6, p = tid & 63;
    out[(b*4 + c)*64 + p] = yb[0][(p >> 3) + 1][(p & 7) + 1][c];
  }
}

extern "C" void kernel_launch(void* const* d_in, const int* in_sizes, int n_in,
                              void* d_out, int out_size, void* d_ws, size_t ws_size,
                              hipStream_t stream) {
  (void)in_sizes; (void)n_in; (void)out_size; (void)d_ws; (void)ws_size;
  made_ar_decode_k<<<dim3(32), dim3(NT), 0, stream>>>(
      (const float*)d_in[0],
      (const float*)d_in[1],  (const float*)d_in[2],
      (const float*)d_in[3],  (const float*)d_in[4],
      (const float*)d_in[5],  (const float*)d_in[6],
      (const float*)d_in[7],  (const float*)d_in[8],
      (const float*)d_in[9],  (const float*)d_in[10],
      (const float*)d_in[11], (const float*)d_in[12],
      (const float*)d_in[13], (const float*)d_in[14],
      (const float*)d_in[15], (const float*)d_in[16],
      (float*)d_out);
}